// Round 4
// baseline (1622.754 us; speedup 1.0000x reference)
//
#include <hip/hip_runtime.h>
#include <math.h>

// ---- problem constants ----
static constexpr int PDIM = 12800;      // 32ch*400
static constexpr int OSD  = 160;        // 10*16

typedef _Float16 hv8  __attribute__((ext_vector_type(8)));
typedef float    f32x4 __attribute__((ext_vector_type(4)));

__device__ __forceinline__ void gload16(const void* g, void* l) {
    __builtin_amdgcn_global_load_lds(
        (const __attribute__((address_space(1))) void*)g,
        (__attribute__((address_space(3))) void*)l, 16, 0, 0);
}

// ---------------- K0: prim_w[co][ci][81] -> Wkf[k][co][ci] fp32 (LDS-tiled) ----------------
__global__ void k_prep_w(const float* __restrict__ w, float* __restrict__ Wkf) {
    __shared__ float s[20736];          // one co-slice: [ci=256][k=81]
    int co = blockIdx.x, t = threadIdx.x;
    const float4* src = (const float4*)(w + (size_t)co*20736);
    float4* d4 = (float4*)s;
    for (int i = t; i < 5184; i += 256) d4[i] = src[i];
    __syncthreads();
    // lane t = ci; stride-81 LDS reads (odd -> conflict-free), coalesced stores
    for (int k = 0; k < 81; ++k)
        Wkf[(size_t)k*65536 + co*256 + t] = s[t*81 + k];
}

// ---------------- K1: conv1 + bias + relu -> ht planes [b][pos][co] fp16 x2 ----------------
__global__ void k_conv1(const float* __restrict__ x, const float* __restrict__ w,
                        const float* __restrict__ bias,
                        _Float16* __restrict__ ht1, _Float16* __restrict__ ht2) {
    __shared__ float sx[1296];
    __shared__ float sw[1296];
    int b = blockIdx.x, cog = blockIdx.y;
    int tid = threadIdx.x;
    for (int i = tid; i < 1296; i += 256) {
        sx[i] = x[b*1296 + i];
        sw[i] = w[cog*1296 + i];
    }
    __syncthreads();
    for (int pos = tid; pos < 784; pos += 256) {
        int y = pos / 28, xx = pos - y*28;
        float acc[16];
        #pragma unroll
        for (int c = 0; c < 16; ++c) acc[c] = 0.f;
        for (int ky = 0; ky < 9; ++ky) {
            #pragma unroll
            for (int kx = 0; kx < 9; ++kx) {
                float xv = sx[(y+ky)*36 + xx + kx];
                #pragma unroll
                for (int c = 0; c < 16; ++c)
                    acc[c] += xv * sw[c*81 + ky*9 + kx];
            }
        }
        #pragma unroll
        for (int c = 0; c < 16; ++c) {
            float r = acc[c] + bias[cog*16 + c];
            r = r > 0.f ? r : 0.f;
            _Float16 h1 = (_Float16)r;
            float q1 = r - (float)h1;
            _Float16 h2 = (_Float16)q1;
            size_t o = ((size_t)b*784 + pos)*256 + cog*16 + c;
            ht1[o] = h1; ht2[o] = h2;
        }
    }
}

// ---------------- K2: primary conv as 81 shifted GEMMs, fp16 2-plane split MFMA ----------------
// Triple-buffered LDS (3x48KB), 2-step-ahead prefetch, counted vmcnt + raw s_barrier.
// BM=128 BN=256 BK=32, 512 thr (8 waves 2x4, 64x64/wave), ksplit=8 atomics.
__global__ __launch_bounds__(512, 2) void k_prim_mfma(
        const _Float16* __restrict__ ht1, const _Float16* __restrict__ ht2,
        const float* __restrict__ Wkf, float* __restrict__ Clin) {
    // per-buffer (halfs): A1 @0 (4096), A2 @4096, B1 @8192 (8192), B2 @16384; BUF=24576
    __shared__ _Float16 lds[73728];
    const int t   = threadIdx.x;
    const int n0  = blockIdx.x * 256;
    const int co0 = blockIdx.y * 128;
    const int z   = blockIdx.z;
    const int klo = (z*81) >> 3, khi = ((z+1)*81) >> 3;
    const int NSTEP = (khi - klo) * 8;

    // staging precompute (source-pre-swizzled k-group, LDS dest lane-linear)
    const int srow = t >> 2, slot = t & 3;
    const int g = slot ^ ((srow >> 1) & 3);
    const size_t aSrcOff = (size_t)(co0 + srow)*256 + slot*8;
    const int aDstOff = srow*32 + g*8;
    int n1 = n0 + srow, n2 = n1 + 128;
    int b1 = n1/400, rr1 = n1 - b1*400, y1 = rr1/20, x1 = rr1 - y1*20;
    int b2 = n2/400, rr2 = n2 - b2*400, y2 = rr2/20, x2 = rr2 - y2*20;
    const size_t bOff1 = ((size_t)b1*784 + y1*28 + x1)*256 + g*8;
    const size_t bOff2 = ((size_t)b2*784 + y2*28 + x2)*256 + g*8;

    // compute-side precompute
    const int l = t & 63, w8 = t >> 6;
    const int wm = w8 >> 2, wn = w8 & 3;
    const int lm = l & 15, lk = l >> 4;
    int aoff[4], boff[4];
    #pragma unroll
    for (int i = 0; i < 4; ++i) {
        int ra = wm*64 + i*16 + lm;
        aoff[i] = ra*32 + ((lk ^ ((ra>>1)&3))*8);
        int rb = wn*64 + i*16 + lm;
        boff[i] = 8192 + rb*32 + ((lk ^ ((rb>>1)&3))*8);
    }

    f32x4 acc[4][4];
    #pragma unroll
    for (int i = 0; i < 4; ++i)
        #pragma unroll
        for (int j = 0; j < 4; ++j) { acc[i][j][0]=0.f; acc[i][j][1]=0.f; acc[i][j][2]=0.f; acc[i][j][3]=0.f; }

    f32x4 av0c, av1c, av0n, av1n;

#define ALOAD(S, V0, V1) { int k_ = klo + ((S) >> 3), c_ = (S) & 7; \
        const float* ap = Wkf + (size_t)k_*65536 + c_*32 + aSrcOff; \
        V0 = *(const f32x4*)ap; V1 = *(const f32x4*)(ap + 4); }

#define BGLOAD(S, LB) { int k_ = klo + ((S) >> 3), c_ = (S) & 7; \
        int spk_ = (k_/9)*28 + (k_ - (k_/9)*9); \
        size_t so = (size_t)spk_*256 + c_*32; \
        gload16(ht1 + bOff1 + so, (LB) + 8192  + t*8); \
        gload16(ht1 + bOff2 + so, (LB) + 12288 + t*8); \
        gload16(ht2 + bOff1 + so, (LB) + 16384 + t*8); \
        gload16(ht2 + bOff2 + so, (LB) + 20480 + t*8); }

#define AWRITE(LB, V0, V1) { hv8 u1, u2; \
        _Pragma("unroll") \
        for (int jj = 0; jj < 8; ++jj) { \
            float v_ = (jj < 4) ? V0[jj] : V1[jj-4]; \
            _Float16 h1 = (_Float16)v_; \
            float q_ = v_ - (float)h1; \
            u1[jj] = h1; u2[jj] = (_Float16)q_; } \
        *(hv8*)((LB) + aDstOff)        = u1; \
        *(hv8*)((LB) + 4096 + aDstOff) = u2; }

#define COMPUTE(L) { hv8 a1[4], a2[4]; \
        _Pragma("unroll") for (int mi = 0; mi < 4; ++mi) { \
            a1[mi] = *(const hv8*)((L) + aoff[mi]); \
            a2[mi] = *(const hv8*)((L) + 4096 + aoff[mi]); } \
        _Pragma("unroll") for (int nj = 0; nj < 4; ++nj) { \
            hv8 q1 = *(const hv8*)((L) + boff[nj]); \
            hv8 q2 = *(const hv8*)((L) + 8192 + boff[nj]); \
            _Pragma("unroll") for (int mi = 0; mi < 4; ++mi) { \
                f32x4 c = acc[mi][nj]; \
                c = __builtin_amdgcn_mfma_f32_16x16x32_f16(a1[mi], q1, c, 0, 0, 0); \
                c = __builtin_amdgcn_mfma_f32_16x16x32_f16(a1[mi], q2, c, 0, 0, 0); \
                c = __builtin_amdgcn_mfma_f32_16x16x32_f16(a2[mi], q1, c, 0, 0, 0); \
                acc[mi][nj] = c; } } }

    _Float16 *b0 = lds, *bb1 = lds + 24576, *bb2 = lds + 49152;

    // prologue: stage steps 0,1; preload A(2)
    ALOAD(0, av0c, av1c); BGLOAD(0, b0);  AWRITE(b0, av0c, av1c);
    ALOAD(1, av0c, av1c); BGLOAD(1, bb1); AWRITE(bb1, av0c, av1c);
    ALOAD(2, av0c, av1c);
    asm volatile("s_waitcnt vmcnt(6)" ::: "memory");     // B(0) complete; B(1)+A(2) in flight
    asm volatile("s_waitcnt lgkmcnt(0)" ::: "memory");
    __builtin_amdgcn_s_barrier();

    for (int j = 0; j < NSTEP; ++j) {
        if (j < NSTEP-3) ALOAD(j+3, av0n, av1n);
        if (j < NSTEP-2) { BGLOAD(j+2, bb2); AWRITE(bb2, av0c, av1c); }
        av0c = av0n; av1c = av1n;
        COMPUTE(b0);
        if (j < NSTEP-1) {
            if (j < NSTEP-3)       { asm volatile("s_waitcnt vmcnt(6)" ::: "memory"); }
            else if (j == NSTEP-3) { asm volatile("s_waitcnt vmcnt(4)" ::: "memory"); }
            else                   { asm volatile("s_waitcnt vmcnt(0)" ::: "memory"); }
            asm volatile("s_waitcnt lgkmcnt(0)" ::: "memory");
            __builtin_amdgcn_s_barrier();
        }
        _Float16* tmp = b0; b0 = bb1; bb1 = bb2; bb2 = tmp;
    }

    // epilogue: atomic accumulate into Clin[co][n]
    #pragma unroll
    for (int mi = 0; mi < 4; ++mi) {
        #pragma unroll
        for (int nj = 0; nj < 4; ++nj) {
            int nn = n0 + wn*64 + nj*16 + lm;
            #pragma unroll
            for (int r = 0; r < 4; ++r) {
                int co = co0 + wm*64 + mi*16 + lk*4 + r;
                atomicAdd(&Clin[(size_t)co*12800 + nn], acc[mi][nj][r]);
            }
        }
    }
#undef ALOAD
#undef BGLOAD
#undef AWRITE
#undef COMPUTE
}

// ---------------- K2b: Clin + bias -> up[b][unit][ch*400+rr], + partial ssq per (b,u) ----------------
__global__ void k_finalize_up(const float* __restrict__ Clin, const float* __restrict__ bias,
                              float* __restrict__ up, float* __restrict__ ssq) {
    __shared__ float r0[256], r1[256];
    int tid = threadIdx.x;
    int e = blockIdx.x*256 + tid;
    int co = e / 12800, n = e - co*12800;
    int unit = co >> 5, ch = co & 31;
    int bn = n / 400, rr = n - bn*400;
    float val = Clin[e] + bias[co];
    up[(size_t)(bn*8 + unit)*PDIM + ch*400 + rr] = val;
    int n0b = (blockIdx.x % 50) * 256;
    int bn0 = n0b / 400;
    int nb  = (bn0+1)*400 - n0b;
    float v2 = val * val;
    bool hi = (tid >= nb);
    r0[tid] = hi ? 0.f : v2;
    r1[tid] = hi ? v2 : 0.f;
    __syncthreads();
    for (int st = 128; st > 0; st >>= 1) {
        if (tid < st) { r0[tid] += r0[tid+st]; r1[tid] += r1[tid+st]; }
        __syncthreads();
    }
    if (tid == 0) {
        atomicAdd(&ssq[bn0*8 + unit], r0[0]);
        if (nb < 256) atomicAdd(&ssq[(bn0+1)*8 + unit], r1[0]);
    }
}

// ---------------- K3: xq[p][b*8+u] = up[b][u][p] * scl(b,u), scl from ssq ----------------
__global__ void k_xq(const float* __restrict__ up, const float* __restrict__ ssq,
                     float* __restrict__ xq) {
    __shared__ float sT[32][257];
    __shared__ float sS[256];
    int p0 = blockIdx.x*32, tid = threadIdx.x;
    {
        float q = ssq[tid];
        sS[tid] = sqrtf(q) / (1.f + q);
    }
    __syncthreads();
    for (int r = 0; r < 32; ++r) {
        int e = r*256 + tid;
        int bu = e >> 5, pi = e & 31;
        sT[pi][bu] = up[(size_t)bu*PDIM + p0 + pi] * sS[bu];
    }
    __syncthreads();
    for (int r = 0; r < 32; ++r)
        xq[(size_t)(p0+r)*256 + tid] = sT[r][tid];
}

// ---------------- K4: softmax-over-P stats per o ----------------
__global__ void k_softmax_stats(const float* __restrict__ bij, float* __restrict__ cstat) {
    __shared__ float red[256];
    int o = blockIdx.x, tid = threadIdx.x;
    float m = -1e30f;
    for (int i = tid; i < PDIM; i += 256) m = fmaxf(m, bij[i*10 + o]);
    red[tid] = m; __syncthreads();
    for (int st = 128; st > 0; st >>= 1) {
        if (tid < st) red[tid] = fmaxf(red[tid], red[tid+st]);
        __syncthreads();
    }
    m = red[0]; __syncthreads();
    float s = 0.f;
    for (int i = tid; i < PDIM; i += 256) s += __expf(bij[i*10 + o] - m);
    red[tid] = s; __syncthreads();
    for (int st = 128; st > 0; st >>= 1) {
        if (tid < st) red[tid] += red[tid+st];
        __syncthreads();
    }
    if (tid == 0) { cstat[o] = m; cstat[16 + o] = red[0]; }
}

// ---------------- K5: pass A — s_j via atomics, u_hat recomputed inline ----------------
__global__ __launch_bounds__(256) void k_route_sj(const float* __restrict__ Wd,
        const float* __restrict__ xq, const float* __restrict__ bij,
        const float* __restrict__ cstat, float* __restrict__ sj, int uniform) {
    int tid = threadIdx.x;
    int bq = tid & 31, g = tid >> 5;
    int os0 = g*20;
    int o0 = os0 >> 4, o1 = o0 + 1;
    float cm0 = 0.f, cm1 = 0.f, rd0 = 0.f, rd1 = 0.f;
    if (!uniform) {
        cm0 = cstat[o0]; cm1 = cstat[o1];
        rd0 = 1.f / cstat[16+o0]; rd1 = 1.f / cstat[16+o1];
    }
    const float uc = 1.f / 12800.f;
    float acc[20];
    #pragma unroll
    for (int i = 0; i < 20; ++i) acc[i] = 0.f;
    int p0 = blockIdx.x * 32;
    for (int p = p0; p < p0+32; ++p) {
        const float4* xr = (const float4*)(xq + (size_t)p*256 + bq*8);
        float4 xa = xr[0], xb = xr[1];
        float c0 = uniform ? uc : __expf(bij[p*10+o0] - cm0) * rd0;
        float c1 = uniform ? uc : __expf(bij[p*10+o1] - cm1) * rd1;
        const float4* wr = (const float4*)(Wd + (size_t)p*1280 + os0*8);
        #pragma unroll
        for (int i = 0; i < 20; ++i) {
            float4 w0 = wr[i*2], w1 = wr[i*2+1];
            float uh = w0.x*xa.x + w0.y*xa.y + w0.z*xa.z + w0.w*xa.w
                     + w1.x*xb.x + w1.y*xb.y + w1.z*xb.z + w1.w*xb.w;
            int oi = (os0 + i) >> 4;
            acc[i] += (oi == o0 ? c0 : c1) * uh;
        }
    }
    float* outp = sj + bq*OSD + os0;
    #pragma unroll
    for (int i = 0; i < 20; ++i) atomicAdd(&outp[i], acc[i]);
}

// ---------------- K6: v = squash(s_j over O axis); optionally write d_out ----------------
__global__ void k_squash_v(const float* __restrict__ sj, float* __restrict__ v,
                           float* __restrict__ dout, int writeOut) {
    __shared__ float ss[640];
    __shared__ float sc[64];
    int tid = threadIdx.x;
    int e = blockIdx.x*640 + tid;
    ss[tid] = sj[e];
    __syncthreads();
    if (tid < 64) {
        int bl = tid >> 4, sl = tid & 15;
        float msq = 0.f;
        #pragma unroll
        for (int o = 0; o < 10; ++o) { float t_ = ss[bl*160 + o*16 + sl]; msq += t_*t_; }
        sc[tid] = sqrtf(msq) / (1.f + msq);
    }
    __syncthreads();
    int bl = tid / 160, r = tid - bl*160, sl = r & 15;
    float val = ss[tid] * sc[bl*16 + sl];
    v[e] = val;
    if (writeOut) dout[e] = val;
}

// ---------------- K7: pass B — b_ij += mean_b sum_s u_hat*v ; also zero sj for next iter ----------------
__global__ __launch_bounds__(320) void k_route_bij(const float* __restrict__ Wd,
        const float* __restrict__ xq, const float* __restrict__ v,
        float* __restrict__ bij, float* __restrict__ sjz) {
    __shared__ float sv[5120];
    __shared__ float sxq[32*260];
    int tid = threadIdx.x;
    int p0 = blockIdx.x*32;
    if (blockIdx.x < 16) sjz[blockIdx.x*320 + tid] = 0.f;   // sj cleared for next route_sj
    for (int e = tid; e < 5120; e += 320) sv[e] = v[e];
    for (int e = tid; e < 8192; e += 320) {
        int pl = e >> 8, bu = e & 255;
        sxq[pl*260 + bu] = xq[(size_t)(p0+pl)*256 + bu];
    }
    __syncthreads();
    int pl = tid / 10, o = tid - pl*10;
    int p = p0 + pl;
    const float4* wr = (const float4*)(Wd + (size_t)p*1280 + o*128);
    float4 wreg[32];
    #pragma unroll
    for (int i = 0; i < 32; ++i) wreg[i] = wr[i];
    float acc = 0.f;
    for (int bq = 0; bq < 32; ++bq) {
        float4 x0 = *(const float4*)&sxq[pl*260 + bq*8];
        float4 x1 = *(const float4*)&sxq[pl*260 + bq*8 + 4];
        #pragma unroll
        for (int sg = 0; sg < 4; ++sg) {
            float4 vs = *(const float4*)&sv[bq*160 + o*16 + sg*4];
            float vsv[4] = {vs.x, vs.y, vs.z, vs.w};
            #pragma unroll
            for (int s4 = 0; s4 < 4; ++s4) {
                int s = sg*4 + s4;
                float4 w0 = wreg[s*2], w1 = wreg[s*2+1];
                float uh = w0.x*x0.x + w0.y*x0.y + w0.z*x0.z + w0.w*x0.w
                         + w1.x*x1.x + w1.y*x1.y + w1.z*x1.z + w1.w*x1.w;
                acc += uh * vsv[s4];
            }
        }
    }
    bij[p*10 + o] += acc * (1.f/32.f);
}

extern "C" void kernel_launch(void* const* d_in, const int* in_sizes, int n_in,
                              void* d_out, int out_size, void* d_ws, size_t ws_size,
                              hipStream_t stream) {
    const float* x   = (const float*)d_in[0];
    const float* c1w = (const float*)d_in[1];
    const float* c1b = (const float*)d_in[2];
    const float* pw  = (const float*)d_in[3];
    const float* pb  = (const float*)d_in[4];
    const float* Wd  = (const float*)d_in[5];
    float* out = (float*)d_out;

    // workspace map (bytes)
    char* wsb = (char*)d_ws;
    _Float16* ht1 = (_Float16*)(wsb);                 // 12,845,056
    _Float16* ht2 = (_Float16*)(wsb + 12845056);      // 12,845,056
    float* Wkf  = (float*)(wsb + 25690112);           // 21,233,664
    float* Clin = (float*)(wsb + 46923776);           // 13,107,200
    char* tailb = wsb + 60030976;
    float* bij   = (float*)tailb;                     // 128000 f
    float* ssq   = bij + 128000;                      // 256 f
    float* sj    = ssq + 256;                         // 5120 f
    float* cstat = sj + 5120;                         // 32 f
    float* vv    = cstat + 32;                        // 5120 f
    // aliases over dead regions:
    float* up  = (float*)(wsb + 25690112);   // over Wkf (dead after GEMM)
    float* xq  = (float*)(wsb);              // over ht planes (dead after GEMM)

    hipMemsetAsync(Clin, 0, 13107200, stream);
    hipMemsetAsync(bij, 0, (128000 + 256 + 5120)*sizeof(float), stream);  // bij + ssq + sj

    k_prep_w<<<256, 256, 0, stream>>>(pw, Wkf);
    k_conv1<<<dim3(32,16), 256, 0, stream>>>(x, c1w, c1b, ht1, ht2);
    k_prim_mfma<<<dim3(50,2,8), 512, 0, stream>>>(ht1, ht2, Wkf, Clin);
    k_finalize_up<<<12800, 256, 0, stream>>>(Clin, pb, up, ssq);
    k_xq<<<400, 256, 0, stream>>>(up, ssq, xq);

    for (int it = 0; it < 3; ++it) {
        if (it > 0)
            k_softmax_stats<<<10, 256, 0, stream>>>(bij, cstat);
        k_route_sj<<<400, 256, 0, stream>>>(Wd, xq, bij, cstat, sj, it == 0 ? 1 : 0);
        k_squash_v<<<8, 640, 0, stream>>>(sj, vv, out, it == 2 ? 1 : 0);
        if (it < 2)
            k_route_bij<<<400, 320, 0, stream>>>(Wd, xq, vv, bij, sj);
    }
}

// Round 5
// 1202.060 us; speedup vs baseline: 1.3500x; 1.3500x over previous
//
#include <hip/hip_runtime.h>
#include <math.h>

// ---- problem constants ----
static constexpr int PDIM = 12800;      // 32ch*400
static constexpr int OSD  = 160;        // 10*16
static constexpr int NBLK_A = 200;      // pass-A blocks (64 p each)

typedef _Float16 hv8  __attribute__((ext_vector_type(8)));
typedef float    f32x4 __attribute__((ext_vector_type(4)));

__device__ __forceinline__ void gload16(const void* g, void* l) {
    __builtin_amdgcn_global_load_lds(
        (const __attribute__((address_space(1))) void*)g,
        (__attribute__((address_space(3))) void*)l, 16, 0, 0);
}

// ---------------- K0: prim_w[co][ci][81] -> Wkf[k][co][ci] fp32 (LDS-tiled) ----------------
__global__ void k_prep_w(const float* __restrict__ w, float* __restrict__ Wkf) {
    __shared__ float s[20736];          // one co-slice: [ci=256][k=81]
    int co = blockIdx.x, t = threadIdx.x;
    const float4* src = (const float4*)(w + (size_t)co*20736);
    float4* d4 = (float4*)s;
    for (int i = t; i < 5184; i += 256) d4[i] = src[i];
    __syncthreads();
    for (int k = 0; k < 81; ++k)
        Wkf[(size_t)k*65536 + co*256 + t] = s[t*81 + k];
}

// ---------------- K1: conv1 + bias + relu -> ht planes [b][pos][co] fp16 x2 ----------------
__global__ void k_conv1(const float* __restrict__ x, const float* __restrict__ w,
                        const float* __restrict__ bias,
                        _Float16* __restrict__ ht1, _Float16* __restrict__ ht2) {
    __shared__ float sx[1296];
    __shared__ float sw[1296];
    int b = blockIdx.x, cog = blockIdx.y;
    int tid = threadIdx.x;
    for (int i = tid; i < 1296; i += 256) {
        sx[i] = x[b*1296 + i];
        sw[i] = w[cog*1296 + i];
    }
    __syncthreads();
    for (int pos = tid; pos < 784; pos += 256) {
        int y = pos / 28, xx = pos - y*28;
        float acc[16];
        #pragma unroll
        for (int c = 0; c < 16; ++c) acc[c] = 0.f;
        for (int ky = 0; ky < 9; ++ky) {
            #pragma unroll
            for (int kx = 0; kx < 9; ++kx) {
                float xv = sx[(y+ky)*36 + xx + kx];
                #pragma unroll
                for (int c = 0; c < 16; ++c)
                    acc[c] += xv * sw[c*81 + ky*9 + kx];
            }
        }
        #pragma unroll
        for (int c = 0; c < 16; ++c) {
            float r = acc[c] + bias[cog*16 + c];
            r = r > 0.f ? r : 0.f;
            _Float16 h1 = (_Float16)r;
            float q1 = r - (float)h1;
            _Float16 h2 = (_Float16)q1;
            size_t o = ((size_t)b*784 + pos)*256 + cog*16 + c;
            ht1[o] = h1; ht2[o] = h2;
        }
    }
}

// ---------------- K2: primary conv as 81 shifted GEMMs, fp16 2-plane split MFMA ----------------
// BM=128 BN=128 BK=32, 512 thr (8 waves 2x4, wave tile 64x32), dbuf 64KB LDS -> 2 blocks/CU.
// ksplit=8 atomics. products kept: a1b1 + a1b2 + a2b1.
__global__ __launch_bounds__(512, 4) void k_prim_mfma(
        const _Float16* __restrict__ ht1, const _Float16* __restrict__ ht2,
        const float* __restrict__ Wkf, float* __restrict__ Clin) {
    // per-buffer (halfs): A1 @0 (4096), A2 @4096, B1 @8192 (4096), B2 @12288; BUF=16384
    __shared__ _Float16 lds[32768];
    const int t   = threadIdx.x;
    const int n0  = blockIdx.x * 128;
    const int co0 = blockIdx.y * 128;
    const int z   = blockIdx.z;
    const int klo = (z*81) >> 3, khi = ((z+1)*81) >> 3;
    const int NSTEP = (khi - klo) * 8;

    // staging precompute (source-pre-swizzled k-group, LDS dest lane-linear)
    const int srow = t >> 2, slot = t & 3;
    const int g = slot ^ ((srow >> 1) & 3);
    const size_t aSrcOff = (size_t)(co0 + srow)*256 + slot*8;
    const int aDstOff = srow*32 + g*8;
    int n1 = n0 + srow;
    int b1 = n1/400, rr1 = n1 - b1*400, y1 = rr1/20, x1 = rr1 - y1*20;
    const size_t bOff1 = ((size_t)b1*784 + y1*28 + x1)*256 + g*8;

    // compute-side precompute
    const int l = t & 63, w8 = t >> 6;
    const int wm = w8 >> 2, wn = w8 & 3;    // wm 0..1 (M 64 each), wn 0..3 (N 32 each)
    const int lm = l & 15, lk = l >> 4;
    int aoff[4], boff[2];
    #pragma unroll
    for (int i = 0; i < 4; ++i) {
        int ra = wm*64 + i*16 + lm;
        aoff[i] = ra*32 + ((lk ^ ((ra>>1)&3))*8);
    }
    #pragma unroll
    for (int j = 0; j < 2; ++j) {
        int rb = wn*32 + j*16 + lm;
        boff[j] = 8192 + rb*32 + ((lk ^ ((rb>>1)&3))*8);
    }

    f32x4 acc[4][2];
    #pragma unroll
    for (int i = 0; i < 4; ++i)
        #pragma unroll
        for (int j = 0; j < 2; ++j) { acc[i][j][0]=0.f; acc[i][j][1]=0.f; acc[i][j][2]=0.f; acc[i][j][3]=0.f; }

    f32x4 av0, av1;

#define ALOAD(S) { int k_ = klo + ((S) >> 3), c_ = (S) & 7; \
        const float* ap = Wkf + (size_t)k_*65536 + c_*32 + aSrcOff; \
        av0 = *(const f32x4*)ap; av1 = *(const f32x4*)(ap + 4); }

#define BGLOAD(S, LB) { int k_ = klo + ((S) >> 3), c_ = (S) & 7; \
        int spk_ = (k_/9)*28 + (k_ - (k_/9)*9); \
        size_t so = (size_t)spk_*256 + c_*32; \
        gload16(ht1 + bOff1 + so, (LB) + 8192  + t*8); \
        gload16(ht2 + bOff1 + so, (LB) + 12288 + t*8); }

#define AWRITE(LB) { hv8 u1, u2; \
        _Pragma("unroll") \
        for (int jj = 0; jj < 8; ++jj) { \
            float v_ = (jj < 4) ? av0[jj] : av1[jj-4]; \
            _Float16 h1 = (_Float16)v_; \
            float q_ = v_ - (float)h1; \
            u1[jj] = h1; u2[jj] = (_Float16)q_; } \
        *(hv8*)((LB) + aDstOff)        = u1; \
        *(hv8*)((LB) + 4096 + aDstOff) = u2; }

#define COMPUTE(L) { hv8 a1[4], a2[4]; \
        _Pragma("unroll") for (int mi = 0; mi < 4; ++mi) { \
            a1[mi] = *(const hv8*)((L) + aoff[mi]); \
            a2[mi] = *(const hv8*)((L) + 4096 + aoff[mi]); } \
        _Pragma("unroll") for (int nj = 0; nj < 2; ++nj) { \
            hv8 q1 = *(const hv8*)((L) + boff[nj]); \
            hv8 q2 = *(const hv8*)((L) + 4096 + boff[nj]); \
            _Pragma("unroll") for (int mi = 0; mi < 4; ++mi) { \
                f32x4 c = acc[mi][nj]; \
                c = __builtin_amdgcn_mfma_f32_16x16x32_f16(a1[mi], q1, c, 0, 0, 0); \
                c = __builtin_amdgcn_mfma_f32_16x16x32_f16(a1[mi], q2, c, 0, 0, 0); \
                c = __builtin_amdgcn_mfma_f32_16x16x32_f16(a2[mi], q1, c, 0, 0, 0); \
                acc[mi][nj] = c; } } }

    // prologue: stage step 0 into buf0
    ALOAD(0); BGLOAD(0, lds); AWRITE(lds);
    __syncthreads();

    for (int s = 0; s < NSTEP; ++s) {
        const int d = s & 1;
        _Float16* Lnext = lds + (d ? 0 : 16384);
        const _Float16* L = lds + (d ? 16384 : 0);
        const bool pf = (s + 1) < NSTEP;
        if (pf) { ALOAD(s+1); BGLOAD(s+1, Lnext); }
        COMPUTE(L);
        if (pf) AWRITE(Lnext);
        __syncthreads();
    }

    // epilogue: atomic accumulate into Clin[co][n]
    #pragma unroll
    for (int mi = 0; mi < 4; ++mi) {
        #pragma unroll
        for (int nj = 0; nj < 2; ++nj) {
            int nn = n0 + wn*32 + nj*16 + lm;
            #pragma unroll
            for (int r = 0; r < 4; ++r) {
                int co = co0 + wm*64 + mi*16 + lk*4 + r;
                atomicAdd(&Clin[(size_t)co*12800 + nn], acc[mi][nj][r]);
            }
        }
    }
#undef ALOAD
#undef BGLOAD
#undef AWRITE
#undef COMPUTE
}

// ---------------- K2b: Clin + bias -> up[b][unit][ch*400+rr], + partial ssq per (b,u) ----------------
__global__ void k_finalize_up(const float* __restrict__ Clin, const float* __restrict__ bias,
                              float* __restrict__ up, float* __restrict__ ssq) {
    __shared__ float r0[256], r1[256];
    int tid = threadIdx.x;
    int e = blockIdx.x*256 + tid;
    int co = e / 12800, n = e - co*12800;
    int unit = co >> 5, ch = co & 31;
    int bn = n / 400, rr = n - bn*400;
    float val = Clin[e] + bias[co];
    up[(size_t)(bn*8 + unit)*PDIM + ch*400 + rr] = val;
    int n0b = (blockIdx.x % 50) * 256;
    int bn0 = n0b / 400;
    int nb  = (bn0+1)*400 - n0b;
    float v2 = val * val;
    bool hi = (tid >= nb);
    r0[tid] = hi ? 0.f : v2;
    r1[tid] = hi ? v2 : 0.f;
    __syncthreads();
    for (int st = 128; st > 0; st >>= 1) {
        if (tid < st) { r0[tid] += r0[tid+st]; r1[tid] += r1[tid+st]; }
        __syncthreads();
    }
    if (tid == 0) {
        atomicAdd(&ssq[bn0*8 + unit], r0[0]);
        if (nb < 256) atomicAdd(&ssq[(bn0+1)*8 + unit], r1[0]);
    }
}

// ---------------- K3: xq[p][b*8+u] = up[b][u][p] * scl(b,u), scl from ssq ----------------
__global__ void k_xq(const float* __restrict__ up, const float* __restrict__ ssq,
                     float* __restrict__ xq) {
    __shared__ float sT[32][257];
    __shared__ float sS[256];
    int p0 = blockIdx.x*32, tid = threadIdx.x;
    {
        float q = ssq[tid];
        sS[tid] = sqrtf(q) / (1.f + q);
    }
    __syncthreads();
    for (int r = 0; r < 32; ++r) {
        int e = r*256 + tid;
        int bu = e >> 5, pi = e & 31;
        sT[pi][bu] = up[(size_t)bu*PDIM + p0 + pi] * sS[bu];
    }
    __syncthreads();
    for (int r = 0; r < 32; ++r)
        xq[(size_t)(p0+r)*256 + tid] = sT[r][tid];
}

// ---------------- K5: pass A — partial s_j; c = exp(bij)/cden (no max, |bij|<<1) ----------------
__global__ __launch_bounds__(256) void k_route_sj(const float* __restrict__ Wd,
        const float* __restrict__ xq, const float* __restrict__ bij,
        const float* __restrict__ cden, float* __restrict__ sjp, int uniform) {
    int tid = threadIdx.x;
    int bq = tid & 31, g = tid >> 5;
    int os0 = g*20;
    int o0 = os0 >> 4, o1 = o0 + 1;
    float rd0, rd1;
    if (uniform) { rd0 = 1.f/12800.f; rd1 = rd0; }
    else         { rd0 = 1.f/cden[o0]; rd1 = 1.f/cden[o1]; }
    float acc[20];
    #pragma unroll
    for (int i = 0; i < 20; ++i) acc[i] = 0.f;
    int p0 = blockIdx.x * 64;
    for (int p = p0; p < p0+64; ++p) {
        const float4* xr = (const float4*)(xq + (size_t)p*256 + bq*8);
        float4 xa = xr[0], xb = xr[1];
        float c0 = uniform ? rd0 : __expf(bij[p*10+o0]) * rd0;
        float c1 = uniform ? rd1 : __expf(bij[p*10+o1]) * rd1;
        const float4* wr = (const float4*)(Wd + (size_t)p*1280 + os0*8);
        #pragma unroll
        for (int i = 0; i < 20; ++i) {
            float4 w0 = wr[i*2], w1 = wr[i*2+1];
            float uh = w0.x*xa.x + w0.y*xa.y + w0.z*xa.z + w0.w*xa.w
                     + w1.x*xb.x + w1.y*xb.y + w1.z*xb.z + w1.w*xb.w;
            int oi = (os0 + i) >> 4;
            acc[i] += (oi == o0 ? c0 : c1) * uh;
        }
    }
    float* outp = sjp + (size_t)blockIdx.x*5120 + bq*OSD + os0;
    #pragma unroll
    for (int i = 0; i < 20; ++i) outp[i] = acc[i];
}

// ---------------- K6: reduce partials -> s_j -> squash over O -> v (+out); zero cden ----------------
__global__ void k_reduce_squash(const float* __restrict__ sjp, float* __restrict__ v,
                                float* __restrict__ cden,
                                float* __restrict__ dout, int writeOut) {
    __shared__ float ss[640];
    __shared__ float sc[64];
    int tid = threadIdx.x;
    if (blockIdx.x == 0 && tid < 10) cden[tid] = 0.f;   // for next route_bij accumulation
    int e = blockIdx.x*640 + tid;
    float s = 0.f;
    for (int k = 0; k < NBLK_A; ++k) s += sjp[(size_t)k*5120 + e];
    ss[tid] = s;
    __syncthreads();
    if (tid < 64) {
        int bl = tid >> 4, sl = tid & 15;
        float msq = 0.f;
        #pragma unroll
        for (int o = 0; o < 10; ++o) { float t_ = ss[bl*160 + o*16 + sl]; msq += t_*t_; }
        sc[tid] = sqrtf(msq) / (1.f + msq);
    }
    __syncthreads();
    int bl = tid / 160, r = tid - bl*160, sl = r & 15;
    float val = ss[tid] * sc[bl*16 + sl];
    v[e] = val;
    if (writeOut) dout[e] = val;
}

// ---------------- K7: pass B — b_ij += mean_b sum_s u_hat*v ; accumulate cden[o] ----------------
__global__ __launch_bounds__(320) void k_route_bij(const float* __restrict__ Wd,
        const float* __restrict__ xq, const float* __restrict__ v,
        float* __restrict__ bij, float* __restrict__ cden) {
    __shared__ float sv[5120];
    __shared__ float sxq[32*260];
    __shared__ float red[320];
    int tid = threadIdx.x;
    int p0 = blockIdx.x*32;
    for (int e = tid; e < 5120; e += 320) sv[e] = v[e];
    for (int e = tid; e < 8192; e += 320) {
        int pl = e >> 8, bu = e & 255;
        sxq[pl*260 + bu] = xq[(size_t)(p0+pl)*256 + bu];
    }
    __syncthreads();
    int pl = tid / 10, o = tid - pl*10;
    int p = p0 + pl;
    const float4* wr = (const float4*)(Wd + (size_t)p*1280 + o*128);
    float4 wreg[32];
    #pragma unroll
    for (int i = 0; i < 32; ++i) wreg[i] = wr[i];
    float acc = 0.f;
    for (int bq = 0; bq < 32; ++bq) {
        float4 x0 = *(const float4*)&sxq[pl*260 + bq*8];
        float4 x1 = *(const float4*)&sxq[pl*260 + bq*8 + 4];
        #pragma unroll
        for (int sg = 0; sg < 4; ++sg) {
            float4 vs = *(const float4*)&sv[bq*160 + o*16 + sg*4];
            float vsv[4] = {vs.x, vs.y, vs.z, vs.w};
            #pragma unroll
            for (int s4 = 0; s4 < 4; ++s4) {
                int s = sg*4 + s4;
                float4 w0 = wreg[s*2], w1 = wreg[s*2+1];
                float uh = w0.x*x0.x + w0.y*x0.y + w0.z*x0.z + w0.w*x0.w
                         + w1.x*x1.x + w1.y*x1.y + w1.z*x1.z + w1.w*x1.w;
                acc += uh * vsv[s4];
            }
        }
    }
    float bn_ = bij[p*10 + o] + acc * (1.f/32.f);
    bij[p*10 + o] = bn_;
    // per-o exp-sum for next iteration's softmax denominator
    red[tid] = __expf(bn_);
    __syncthreads();
    if (tid < 10) {
        float s_ = 0.f;
        #pragma unroll
        for (int j = 0; j < 32; ++j) s_ += red[tid + j*10];
        atomicAdd(&cden[tid], s_);
    }
}

extern "C" void kernel_launch(void* const* d_in, const int* in_sizes, int n_in,
                              void* d_out, int out_size, void* d_ws, size_t ws_size,
                              hipStream_t stream) {
    const float* x   = (const float*)d_in[0];
    const float* c1w = (const float*)d_in[1];
    const float* c1b = (const float*)d_in[2];
    const float* pw  = (const float*)d_in[3];
    const float* pb  = (const float*)d_in[4];
    const float* Wd  = (const float*)d_in[5];
    float* out = (float*)d_out;

    // workspace map (bytes)
    char* wsb = (char*)d_ws;
    _Float16* ht1 = (_Float16*)(wsb);                 // 12,845,056
    _Float16* ht2 = (_Float16*)(wsb + 12845056);      // 12,845,056
    float* Wkf  = (float*)(wsb + 25690112);           // 21,233,664
    float* Clin = (float*)(wsb + 46923776);           // 13,107,200
    char* tailb = wsb + 60030976;
    float* bij   = (float*)tailb;                     // 128000 f
    float* ssq   = bij + 128000;                      // 256 f
    float* cden  = ssq + 256;                         // 16 f
    float* vv    = cden + 16;                         // 5120 f
    // aliases over dead regions:
    float* up  = (float*)(wsb + 25690112);   // over Wkf (dead after GEMM)
    float* xq  = (float*)(wsb);              // over ht planes (dead after GEMM)
    float* sjp = (float*)(wsb + 46923776);   // over Clin (dead after finalize)

    hipMemsetAsync(Clin, 0, 13107200, stream);
    hipMemsetAsync(bij, 0, (128000 + 256)*sizeof(float), stream);  // bij + ssq

    k_prep_w<<<256, 256, 0, stream>>>(pw, Wkf);
    k_conv1<<<dim3(32,16), 256, 0, stream>>>(x, c1w, c1b, ht1, ht2);
    k_prim_mfma<<<dim3(100,2,8), 512, 0, stream>>>(ht1, ht2, Wkf, Clin);
    k_finalize_up<<<12800, 256, 0, stream>>>(Clin, pb, up, ssq);
    k_xq<<<400, 256, 0, stream>>>(up, ssq, xq);

    for (int it = 0; it < 3; ++it) {
        k_route_sj<<<NBLK_A, 256, 0, stream>>>(Wd, xq, bij, cden, sjp, it == 0 ? 1 : 0);
        k_reduce_squash<<<8, 640, 0, stream>>>(sjp, vv, cden, out, it == 2 ? 1 : 0);
        if (it < 2)
            k_route_bij<<<400, 320, 0, stream>>>(Wd, xq, vv, bij, cden);
    }
}

// Round 6
// 1085.624 us; speedup vs baseline: 1.4948x; 1.1073x over previous
//
#include <hip/hip_runtime.h>
#include <math.h>

// ---- problem constants ----
static constexpr int PDIM = 12800;      // 32ch*400
static constexpr int OSD  = 160;        // 10*16
static constexpr int NBLK_A = 200;      // pass-A p-blocks (64 p each)

typedef _Float16 hv8  __attribute__((ext_vector_type(8)));
typedef float    f32x4 __attribute__((ext_vector_type(4)));

__device__ __forceinline__ void gload16(const void* g, void* l) {
    __builtin_amdgcn_global_load_lds(
        (const __attribute__((address_space(1))) void*)g,
        (__attribute__((address_space(3))) void*)l, 16, 0, 0);
}

// ---------------- K0: prim_w[co][ci][81] -> Wk1/Wk2[k][co][ci] fp16 planes ----------------
__global__ void k_prep_w(const float* __restrict__ w,
                         _Float16* __restrict__ Wk1, _Float16* __restrict__ Wk2) {
    __shared__ float s[20736];          // one co-slice: [ci=256][k=81]
    int co = blockIdx.x, t = threadIdx.x;
    const float4* src = (const float4*)(w + (size_t)co*20736);
    float4* d4 = (float4*)s;
    for (int i = t; i < 5184; i += 256) d4[i] = src[i];
    __syncthreads();
    // lane t = ci; stride-81 LDS reads (odd -> conflict-free), coalesced 2B stores
    for (int k = 0; k < 81; ++k) {
        float val = s[t*81 + k];
        _Float16 h1 = (_Float16)val;
        _Float16 h2 = (_Float16)(val - (float)h1);
        size_t o = (size_t)k*65536 + co*256 + t;
        Wk1[o] = h1;
        Wk2[o] = h2;
    }
}

// ---------------- K1: conv1 + bias + relu -> ht planes [b][pos][co] fp16 x2 ----------------
__global__ void k_conv1(const float* __restrict__ x, const float* __restrict__ w,
                        const float* __restrict__ bias,
                        _Float16* __restrict__ ht1, _Float16* __restrict__ ht2) {
    __shared__ float sx[1296];
    __shared__ float sw[1296];
    int b = blockIdx.x, cog = blockIdx.y;
    int tid = threadIdx.x;
    for (int i = tid; i < 1296; i += 256) {
        sx[i] = x[b*1296 + i];
        sw[i] = w[cog*1296 + i];
    }
    __syncthreads();
    for (int pos = tid; pos < 784; pos += 256) {
        int y = pos / 28, xx = pos - y*28;
        float acc[16];
        #pragma unroll
        for (int c = 0; c < 16; ++c) acc[c] = 0.f;
        for (int ky = 0; ky < 9; ++ky) {
            #pragma unroll
            for (int kx = 0; kx < 9; ++kx) {
                float xv = sx[(y+ky)*36 + xx + kx];
                #pragma unroll
                for (int c = 0; c < 16; ++c)
                    acc[c] += xv * sw[c*81 + ky*9 + kx];
            }
        }
        #pragma unroll
        for (int c = 0; c < 16; ++c) {
            float r = acc[c] + bias[cog*16 + c];
            r = r > 0.f ? r : 0.f;
            _Float16 h1 = (_Float16)r;
            float q1 = r - (float)h1;
            _Float16 h2 = (_Float16)q1;
            size_t o = ((size_t)b*784 + pos)*256 + cog*16 + c;
            ht1[o] = h1; ht2[o] = h2;
        }
    }
}

// ---------------- K2: primary conv as 81 shifted GEMMs, fp16 2-plane split MFMA ----------------
// BM=128 BN=128 BK=32, 512 thr (8 waves 2x4, wave tile 64x32), dbuf 64KB LDS -> 2 blocks/CU.
// A and B both staged via global_load_lds (A planes pre-split in k_prep_w -> no VALU convert).
// ksplit=8 atomics. products kept: a1b1 + a1b2 + a2b1.
__global__ __launch_bounds__(512, 4) void k_prim_mfma(
        const _Float16* __restrict__ ht1, const _Float16* __restrict__ ht2,
        const _Float16* __restrict__ Wk1, const _Float16* __restrict__ Wk2,
        float* __restrict__ Clin) {
    // per-buffer (halfs): A1 @0 (4096), A2 @4096, B1 @8192 (4096), B2 @12288; BUF=16384
    __shared__ _Float16 lds[32768];
    const int t   = threadIdx.x;
    const int n0  = blockIdx.x * 128;
    const int co0 = blockIdx.y * 128;
    const int z   = blockIdx.z;
    const int klo = (z*81) >> 3, khi = ((z+1)*81) >> 3;
    const int NSTEP = (khi - klo) * 8;

    // staging precompute (source-pre-swizzled k-group, LDS dest lane-linear)
    const int srow = t >> 2, slot = t & 3;
    const int g = slot ^ ((srow >> 1) & 3);
    const size_t aSrcOff = (size_t)(co0 + srow)*256 + g*8;   // A: row=co, swizzled ci-group
    const int n1 = n0 + srow;
    const int b1 = n1/400, rr1 = n1 - b1*400, y1 = rr1/20, x1 = rr1 - y1*20;
    const size_t bOff1 = ((size_t)b1*784 + y1*28 + x1)*256 + g*8;

    // compute-side precompute
    const int l = t & 63, w8 = t >> 6;
    const int wm = w8 >> 2, wn = w8 & 3;    // wm 0..1 (M 64 each), wn 0..3 (N 32 each)
    const int lm = l & 15, lk = l >> 4;
    int aoff[4], boff[2];
    #pragma unroll
    for (int i = 0; i < 4; ++i) {
        int ra = wm*64 + i*16 + lm;
        aoff[i] = ra*32 + ((lk ^ ((ra>>1)&3))*8);
    }
    #pragma unroll
    for (int j = 0; j < 2; ++j) {
        int rb = wn*32 + j*16 + lm;
        boff[j] = 8192 + rb*32 + ((lk ^ ((rb>>1)&3))*8);
    }

    f32x4 acc[4][2];
    #pragma unroll
    for (int i = 0; i < 4; ++i)
        #pragma unroll
        for (int j = 0; j < 2; ++j) { acc[i][j][0]=0.f; acc[i][j][1]=0.f; acc[i][j][2]=0.f; acc[i][j][3]=0.f; }

#define ASTAGE(S, LB) { int k_ = klo + ((S) >> 3), c_ = (S) & 7; \
        size_t ao = (size_t)k_*65536 + c_*32 + aSrcOff; \
        gload16(Wk1 + ao, (LB) + t*8); \
        gload16(Wk2 + ao, (LB) + 4096 + t*8); }

#define BGLOAD(S, LB) { int k_ = klo + ((S) >> 3), c_ = (S) & 7; \
        int spk_ = (k_/9)*28 + (k_ - (k_/9)*9); \
        size_t so = (size_t)spk_*256 + c_*32; \
        gload16(ht1 + bOff1 + so, (LB) + 8192  + t*8); \
        gload16(ht2 + bOff1 + so, (LB) + 12288 + t*8); }

#define COMPUTE(L) { hv8 a1[4], a2[4]; \
        _Pragma("unroll") for (int mi = 0; mi < 4; ++mi) { \
            a1[mi] = *(const hv8*)((L) + aoff[mi]); \
            a2[mi] = *(const hv8*)((L) + 4096 + aoff[mi]); } \
        _Pragma("unroll") for (int nj = 0; nj < 2; ++nj) { \
            hv8 q1 = *(const hv8*)((L) + boff[nj]); \
            hv8 q2 = *(const hv8*)((L) + 4096 + boff[nj]); \
            _Pragma("unroll") for (int mi = 0; mi < 4; ++mi) { \
                f32x4 c = acc[mi][nj]; \
                c = __builtin_amdgcn_mfma_f32_16x16x32_f16(a1[mi], q1, c, 0, 0, 0); \
                c = __builtin_amdgcn_mfma_f32_16x16x32_f16(a1[mi], q2, c, 0, 0, 0); \
                c = __builtin_amdgcn_mfma_f32_16x16x32_f16(a2[mi], q1, c, 0, 0, 0); \
                acc[mi][nj] = c; } } }

    // prologue: stage step 0 into buf0
    ASTAGE(0, lds); BGLOAD(0, lds);
    __syncthreads();

    for (int s = 0; s < NSTEP; ++s) {
        const int d = s & 1;
        _Float16* Lnext = lds + (d ? 0 : 16384);
        const _Float16* L = lds + (d ? 16384 : 0);
        if ((s + 1) < NSTEP) { ASTAGE(s+1, Lnext); BGLOAD(s+1, Lnext); }
        COMPUTE(L);
        __syncthreads();
    }

    // epilogue: atomic accumulate into Clin[co][n]
    #pragma unroll
    for (int mi = 0; mi < 4; ++mi) {
        #pragma unroll
        for (int nj = 0; nj < 2; ++nj) {
            int nn = n0 + wn*32 + nj*16 + lm;
            #pragma unroll
            for (int r = 0; r < 4; ++r) {
                int co = co0 + wm*64 + mi*16 + lk*4 + r;
                atomicAdd(&Clin[(size_t)co*12800 + nn], acc[mi][nj][r]);
            }
        }
    }
#undef ASTAGE
#undef BGLOAD
#undef COMPUTE
}

// ---------------- K2b: Clin + bias -> up[b][unit][ch*400+rr], + partial ssq per (b,u) ----------------
__global__ void k_finalize_up(const float* __restrict__ Clin, const float* __restrict__ bias,
                              float* __restrict__ up, float* __restrict__ ssq) {
    __shared__ float r0[256], r1[256];
    int tid = threadIdx.x;
    int e = blockIdx.x*256 + tid;
    int co = e / 12800, n = e - co*12800;
    int unit = co >> 5, ch = co & 31;
    int bn = n / 400, rr = n - bn*400;
    float val = Clin[e] + bias[co];
    up[(size_t)(bn*8 + unit)*PDIM + ch*400 + rr] = val;
    int n0b = (blockIdx.x % 50) * 256;
    int bn0 = n0b / 400;
    int nb  = (bn0+1)*400 - n0b;
    float v2 = val * val;
    bool hi = (tid >= nb);
    r0[tid] = hi ? 0.f : v2;
    r1[tid] = hi ? v2 : 0.f;
    __syncthreads();
    for (int st = 128; st > 0; st >>= 1) {
        if (tid < st) { r0[tid] += r0[tid+st]; r1[tid] += r1[tid+st]; }
        __syncthreads();
    }
    if (tid == 0) {
        atomicAdd(&ssq[bn0*8 + unit], r0[0]);
        if (nb < 256) atomicAdd(&ssq[(bn0+1)*8 + unit], r1[0]);
    }
}

// ---------------- K3: xq[p][b*8+u] = up[b][u][p] * scl(b,u), scl from ssq ----------------
__global__ void k_xq(const float* __restrict__ up, const float* __restrict__ ssq,
                     float* __restrict__ xq) {
    __shared__ float sT[32][257];
    __shared__ float sS[256];
    int p0 = blockIdx.x*32, tid = threadIdx.x;
    {
        float q = ssq[tid];
        sS[tid] = sqrtf(q) / (1.f + q);
    }
    __syncthreads();
    for (int r = 0; r < 32; ++r) {
        int e = r*256 + tid;
        int bu = e >> 5, pi = e & 31;
        sT[pi][bu] = up[(size_t)bu*PDIM + p0 + pi] * sS[bu];
    }
    __syncthreads();
    for (int r = 0; r < 32; ++r)
        xq[(size_t)(p0+r)*256 + tid] = sT[r][tid];
}

// ---------------- K5: pass A — partial s_j; c = exp(bij)/cden (no max, |bij|<<1) ----------------
// grid (NBLK_A, 2): x = 64-p block, y = 80-os half. 256 thr = 8 g (10 os each) x 32 bq.
__global__ __launch_bounds__(256) void k_route_sj(const float* __restrict__ Wd,
        const float* __restrict__ xq, const float* __restrict__ bij,
        const float* __restrict__ cden, float* __restrict__ sjp, int uniform) {
    int tid = threadIdx.x;
    int bq = tid & 31, g = tid >> 5;
    int os0 = blockIdx.y*80 + g*10;
    int o0 = os0 >> 4, o1 = (os0 + 9) >> 4;    // 10-wide window spans 1 or 2 o's
    float rd0, rd1;
    if (uniform) { rd0 = 1.f/12800.f; rd1 = rd0; }
    else         { rd0 = 1.f/cden[o0]; rd1 = 1.f/cden[o1]; }
    float acc[10];
    #pragma unroll
    for (int i = 0; i < 10; ++i) acc[i] = 0.f;
    int p0 = blockIdx.x * 64;
    for (int p = p0; p < p0+64; ++p) {
        const float4* xr = (const float4*)(xq + (size_t)p*256 + bq*8);
        float4 xa = xr[0], xb = xr[1];
        float c0 = uniform ? rd0 : __expf(bij[p*10+o0]) * rd0;
        float c1 = (o1 == o0) ? c0 : (uniform ? rd1 : __expf(bij[p*10+o1]) * rd1);
        const float4* wr = (const float4*)(Wd + (size_t)p*1280 + os0*8);
        #pragma unroll
        for (int i = 0; i < 10; ++i) {
            float4 w0 = wr[i*2], w1 = wr[i*2+1];
            float uh = w0.x*xa.x + w0.y*xa.y + w0.z*xa.z + w0.w*xa.w
                     + w1.x*xb.x + w1.y*xb.y + w1.z*xb.z + w1.w*xb.w;
            int oi = (os0 + i) >> 4;
            acc[i] += (oi == o0 ? c0 : c1) * uh;
        }
    }
    float* outp = sjp + (size_t)blockIdx.x*5120 + bq*OSD + os0;
    #pragma unroll
    for (int i = 0; i < 10; ++i) outp[i] = acc[i];
}

// ---------------- K6: reduce partials -> s_j -> squash over O -> v (+out); zero cden ----------------
__global__ void k_reduce_squash(const float* __restrict__ sjp, float* __restrict__ v,
                                float* __restrict__ cden,
                                float* __restrict__ dout, int writeOut) {
    __shared__ float ss[640];
    __shared__ float sc[64];
    int tid = threadIdx.x;
    if (blockIdx.x == 0 && tid < 10) cden[tid] = 0.f;   // for next route_bij accumulation
    int e = blockIdx.x*640 + tid;
    float s = 0.f;
    for (int k = 0; k < NBLK_A; ++k) s += sjp[(size_t)k*5120 + e];
    ss[tid] = s;
    __syncthreads();
    if (tid < 64) {
        int bl = tid >> 4, sl = tid & 15;
        float msq = 0.f;
        #pragma unroll
        for (int o = 0; o < 10; ++o) { float t_ = ss[bl*160 + o*16 + sl]; msq += t_*t_; }
        sc[tid] = sqrtf(msq) / (1.f + msq);
    }
    __syncthreads();
    int bl = tid / 160, r = tid - bl*160, sl = r & 15;
    float val = ss[tid] * sc[bl*16 + sl];
    v[e] = val;
    if (writeOut) dout[e] = val;
}

// ---------------- K7: pass B — b_ij += mean_b sum_s u_hat*v ; accumulate cden[o] ----------------
__global__ __launch_bounds__(320) void k_route_bij(const float* __restrict__ Wd,
        const float* __restrict__ xq, const float* __restrict__ v,
        float* __restrict__ bij, float* __restrict__ cden) {
    __shared__ float sv[5120];
    __shared__ float sxq[32*260];
    __shared__ float red[320];
    int tid = threadIdx.x;
    int p0 = blockIdx.x*32;
    for (int e = tid; e < 5120; e += 320) sv[e] = v[e];
    for (int e = tid; e < 8192; e += 320) {
        int pl = e >> 8, bu = e & 255;
        sxq[pl*260 + bu] = xq[(size_t)(p0+pl)*256 + bu];
    }
    __syncthreads();
    int pl = tid / 10, o = tid - pl*10;
    int p = p0 + pl;
    const float4* wr = (const float4*)(Wd + (size_t)p*1280 + o*128);
    float4 wreg[32];
    #pragma unroll
    for (int i = 0; i < 32; ++i) wreg[i] = wr[i];
    float acc = 0.f;
    for (int bq = 0; bq < 32; ++bq) {
        float4 x0 = *(const float4*)&sxq[pl*260 + bq*8];
        float4 x1 = *(const float4*)&sxq[pl*260 + bq*8 + 4];
        #pragma unroll
        for (int sg = 0; sg < 4; ++sg) {
            float4 vs = *(const float4*)&sv[bq*160 + o*16 + sg*4];
            float vsv[4] = {vs.x, vs.y, vs.z, vs.w};
            #pragma unroll
            for (int s4 = 0; s4 < 4; ++s4) {
                int s = sg*4 + s4;
                float4 w0 = wreg[s*2], w1 = wreg[s*2+1];
                float uh = w0.x*x0.x + w0.y*x0.y + w0.z*x0.z + w0.w*x0.w
                         + w1.x*x1.x + w1.y*x1.y + w1.z*x1.z + w1.w*x1.w;
                acc += uh * vsv[s4];
            }
        }
    }
    float bn_ = bij[p*10 + o] + acc * (1.f/32.f);
    bij[p*10 + o] = bn_;
    // per-o exp-sum for next iteration's softmax denominator
    red[tid] = __expf(bn_);
    __syncthreads();
    if (tid < 10) {
        float s_ = 0.f;
        #pragma unroll
        for (int j = 0; j < 32; ++j) s_ += red[tid + j*10];
        atomicAdd(&cden[tid], s_);
    }
}

extern "C" void kernel_launch(void* const* d_in, const int* in_sizes, int n_in,
                              void* d_out, int out_size, void* d_ws, size_t ws_size,
                              hipStream_t stream) {
    const float* x   = (const float*)d_in[0];
    const float* c1w = (const float*)d_in[1];
    const float* c1b = (const float*)d_in[2];
    const float* pw  = (const float*)d_in[3];
    const float* pb  = (const float*)d_in[4];
    const float* Wd  = (const float*)d_in[5];
    float* out = (float*)d_out;

    // workspace map (bytes)
    char* wsb = (char*)d_ws;
    _Float16* ht1 = (_Float16*)(wsb);                 // 12,845,056
    _Float16* ht2 = (_Float16*)(wsb + 12845056);      // 12,845,056
    _Float16* Wk1 = (_Float16*)(wsb + 25690112);      // 10,616,832
    _Float16* Wk2 = (_Float16*)(wsb + 36306944);      // 10,616,832
    float* Clin = (float*)(wsb + 46923776);           // 13,107,200
    char* tailb = wsb + 60030976;
    float* bij   = (float*)tailb;                     // 128000 f
    float* ssq   = bij + 128000;                      // 256 f
    float* cden  = ssq + 256;                         // 16 f
    float* vv    = cden + 16;                         // 5120 f
    // aliases over dead regions:
    float* up  = (float*)(wsb + 25690112);   // over Wk1+Wk2 (dead after GEMM)
    float* xq  = (float*)(wsb);              // over ht planes (dead after GEMM)
    float* sjp = (float*)(wsb + 46923776);   // over Clin (dead after finalize)

    hipMemsetAsync(Clin, 0, 13107200, stream);
    hipMemsetAsync(bij, 0, (128000 + 256)*sizeof(float), stream);  // bij + ssq

    k_prep_w<<<256, 256, 0, stream>>>(pw, Wk1, Wk2);
    k_conv1<<<dim3(32,16), 256, 0, stream>>>(x, c1w, c1b, ht1, ht2);
    k_prim_mfma<<<dim3(100,2,8), 512, 0, stream>>>(ht1, ht2, Wk1, Wk2, Clin);
    k_finalize_up<<<12800, 256, 0, stream>>>(Clin, pb, up, ssq);
    k_xq<<<400, 256, 0, stream>>>(up, ssq, xq);

    for (int it = 0; it < 3; ++it) {
        k_route_sj<<<dim3(NBLK_A,2), 256, 0, stream>>>(Wd, xq, bij, cden, sjp, it == 0 ? 1 : 0);
        k_reduce_squash<<<8, 640, 0, stream>>>(sjp, vv, cden, out, it == 2 ? 1 : 0);
        if (it < 2)
            k_route_bij<<<400, 320, 0, stream>>>(Wd, xq, vv, bij, cden);
    }
}